// Round 2
// baseline (423.175 us; speedup 1.0000x reference)
//
#include <hip/hip_runtime.h>

// ---------------------------------------------------------------------------
// FlashAttention block: out = proj(causal_attn(qkv(x)))
// B=2, T=2048, D=1024, H=16, dhead=64.  All GEMMs + attention in bf16 MFMA
// (16x16x32), fp32 accumulate.  fp32 output.
// ---------------------------------------------------------------------------

#define B_   2
#define T_   2048
#define D_   1024
#define H_   16
#define DH_  64
#define M_   (B_ * T_)       // 4096
#define N1_  (3 * D_)        // 3072
// qscale folds 1/sqrt(dhead) and log2(e) so softmax uses native exp2
#define QSCALE (0.125f * 1.44269504088896340736f)

typedef __bf16 bf16x8 __attribute__((ext_vector_type(8)));
typedef __bf16 bf16x4 __attribute__((ext_vector_type(4)));
typedef float  f32x4  __attribute__((ext_vector_type(4)));

#define MFMA16(a, b, c) __builtin_amdgcn_mfma_f32_16x16x32_bf16((a), (b), (c), 0, 0, 0)

// -------------------------------- converts ---------------------------------

__global__ void f32_to_bf16_kernel(const float* __restrict__ in,
                                   __bf16* __restrict__ out, int n) {
    int i = (blockIdx.x * blockDim.x + threadIdx.x) * 4;
    if (i + 3 < n) {
        float4 f = *(const float4*)(in + i);
        bf16x4 o;
        o[0] = (__bf16)f.x; o[1] = (__bf16)f.y; o[2] = (__bf16)f.z; o[3] = (__bf16)f.w;
        *(bf16x4*)(out + i) = o;
    }
}

// in: fp32 [R][C]  ->  out: bf16 [C][R]
__global__ void transpose_bf16_kernel(const float* __restrict__ in,
                                      __bf16* __restrict__ out, int R, int C) {
    __shared__ float tile[32][33];
    int tx = threadIdx.x;          // 0..31
    int ty = threadIdx.y;          // 0..7
    int c0 = blockIdx.x * 32;
    int r0 = blockIdx.y * 32;
#pragma unroll
    for (int i = 0; i < 4; i++)
        tile[ty + i * 8][tx] = in[(size_t)(r0 + ty + i * 8) * C + c0 + tx];
    __syncthreads();
#pragma unroll
    for (int i = 0; i < 4; i++)
        out[(size_t)(c0 + ty + i * 8) * R + r0 + tx] = (__bf16)tile[tx][ty + i * 8];
}

// ------------------------------- MFMA GEMM ---------------------------------
// C[M][N] = A[M][K] @ Bt[N][K]^T + bias.  128x128 tile, 256 threads (4 waves),
// each wave a 64x64 region as 4x4 frags of 16x16.  BK=32 (one MFMA K-step).
// EPI 0: scatter to Q (scaled), K, Vt (bf16).  EPI 1: fp32 out + bias.

template <int EPI>
__global__ __launch_bounds__(256) void gemm_bt_kernel(
    const __bf16* __restrict__ A, const __bf16* __restrict__ Bt,
    const float* __restrict__ bias, float* __restrict__ Cout,
    __bf16* __restrict__ Q, __bf16* __restrict__ Kb, __bf16* __restrict__ Vt,
    int M, int N, int K) {
    // padded stride 36 elems (72B): 16-row b128 reads land on distinct banks
    __shared__ __bf16 As[128 * 36];
    __shared__ __bf16 Bs[128 * 36];

    const int tid  = threadIdx.x;
    const int lane = tid & 63;
    const int wave = tid >> 6;
    const int lo   = lane & 15;
    const int qd   = lane >> 4;
    const int wm   = (wave >> 1) * 64;
    const int wn   = (wave & 1) * 64;
    const int m0   = blockIdx.y * 128;
    const int n0   = blockIdx.x * 128;

    // staging: thread t loads 16B chunk (row=t>>2, koff=(t&3)*8) for rows
    // [0,64) and [64,128) of both tiles
    const int row_a = tid >> 2;
    const int ko    = (tid & 3) * 8;
    const __bf16* gA = A + (size_t)(m0 + row_a) * K + ko;
    const __bf16* gB = Bt + (size_t)(n0 + row_a) * K + ko;
    char* asb = (char*)As;
    char* bsb = (char*)Bs;
    const int lds1 = row_a * 72 + (tid & 3) * 16;
    const int lds2 = (row_a + 64) * 72 + (tid & 3) * 16;

    f32x4 acc[4][4] = {};

    for (int k0 = 0; k0 < K; k0 += 32) {
        uint4 a0 = *(const uint4*)(gA + k0);
        uint4 a1 = *(const uint4*)(gA + (size_t)64 * K + k0);
        uint4 b0 = *(const uint4*)(gB + k0);
        uint4 b1 = *(const uint4*)(gB + (size_t)64 * K + k0);
        __syncthreads();   // previous iter's frag reads done before overwrite
        *(uint4*)(asb + lds1) = a0;
        *(uint4*)(asb + lds2) = a1;
        *(uint4*)(bsb + lds1) = b0;
        *(uint4*)(bsb + lds2) = b1;
        __syncthreads();
        bf16x8 af[4], bfr[4];
#pragma unroll
        for (int i = 0; i < 4; i++)
            af[i] = *(const bf16x8*)(As + (wm + i * 16 + lo) * 36 + qd * 8);
#pragma unroll
        for (int j = 0; j < 4; j++)
            bfr[j] = *(const bf16x8*)(Bs + (wn + j * 16 + lo) * 36 + qd * 8);
#pragma unroll
        for (int i = 0; i < 4; i++)
#pragma unroll
            for (int j = 0; j < 4; j++)
                acc[i][j] = MFMA16(af[i], bfr[j], acc[i][j]);
    }

#pragma unroll
    for (int i = 0; i < 4; i++) {
#pragma unroll
        for (int j = 0; j < 4; j++) {
#pragma unroll
            for (int r = 0; r < 4; r++) {
                int gm = m0 + wm + i * 16 + qd * 4 + r;   // C/D row
                int gn = n0 + wn + j * 16 + lo;           // C/D col
                float v = acc[i][j][r] + bias[gn];
                if (EPI == 1) {
                    Cout[(size_t)gm * N + gn] = v;
                } else {
                    int which = gn >> 10;                 // 0=q 1=k 2=v
                    int bh = ((gm >> 11) << 4) + ((gn >> 6) & 15);
                    int dd = gn & 63;
                    int t  = gm & (T_ - 1);
                    if (which == 0)
                        Q[((size_t)bh * T_ + t) * DH_ + dd] = (__bf16)(v * QSCALE);
                    else if (which == 1)
                        Kb[((size_t)bh * T_ + t) * DH_ + dd] = (__bf16)v;
                    else
                        Vt[((size_t)bh * DH_ + dd) * T_ + t] = (__bf16)v;
                }
            }
        }
    }
}

// ---------------------------- flash attention ------------------------------
// One wave per 16-row Q tile (4 independent waves per block; no __syncthreads
// since trip counts differ).  32-key tiles; QK^T and PV via 16x16x32 bf16
// MFMA; online softmax in exp2 domain; P goes C-layout -> A-layout through a
// per-wave LDS buffer with explicit lgkmcnt fences.

__global__ __launch_bounds__(256) void attn_kernel(
    const __bf16* __restrict__ Q,   // [BH][T][64], pre-scaled
    const __bf16* __restrict__ Kb,  // [BH][T][64]
    const __bf16* __restrict__ Vt,  // [BH][64][T]
    __bf16* __restrict__ O) {       // [B][T][H*64]
    __shared__ __bf16 plds_all[4][16][40];   // stride 40: 2-way-bank (free)

    const int wave = threadIdx.x >> 6;
    const int lane = threadIdx.x & 63;
    const int lo   = lane & 15;
    const int qd   = lane >> 4;
    const int bh   = blockIdx.y;
    const int b    = bh >> 4;
    const int h    = bh & 15;
    const int q0   = blockIdx.x * 64 + wave * 16;

    const __bf16* Qh = Q + (size_t)bh * T_ * DH_;
    const __bf16* Kh = Kb + (size_t)bh * T_ * DH_;
    const __bf16* Vh = Vt + (size_t)bh * DH_ * T_;
    __bf16(*plds)[40] = plds_all[wave];

    // Q A-frags: lane holds Q[q0+lo][chunk*32 + qd*8 + j]
    bf16x8 qa0 = *(const bf16x8*)(Qh + (size_t)(q0 + lo) * DH_ + qd * 8);
    bf16x8 qa1 = *(const bf16x8*)(Qh + (size_t)(q0 + lo) * DH_ + 32 + qd * 8);

    f32x4 oacc[4] = {};
    float mrow[4], lrow[4];
#pragma unroll
    for (int r = 0; r < 4; r++) { mrow[r] = -1e30f; lrow[r] = 0.0f; }

    const int qrow_base = q0 + qd * 4;
    const int qend = q0 + 15;

    for (int j0 = 0; j0 <= qend; j0 += 32) {
        // ---- S = Q @ K^T for 32 keys (two 16-col halves) ----
        f32x4 s0 = {}, s1 = {};
        {
            bf16x8 kb;
            kb = *(const bf16x8*)(Kh + (size_t)(j0 + lo) * DH_ + qd * 8);
            s0 = MFMA16(qa0, kb, s0);
            kb = *(const bf16x8*)(Kh + (size_t)(j0 + lo) * DH_ + 32 + qd * 8);
            s0 = MFMA16(qa1, kb, s0);
            kb = *(const bf16x8*)(Kh + (size_t)(j0 + 16 + lo) * DH_ + qd * 8);
            s1 = MFMA16(qa0, kb, s1);
            kb = *(const bf16x8*)(Kh + (size_t)(j0 + 16 + lo) * DH_ + 32 + qd * 8);
            s1 = MFMA16(qa1, kb, s1);
        }
        // ---- causal mask ----
        float sc0[4], sc1[4];
#pragma unroll
        for (int r = 0; r < 4; r++) {
            int qq = qrow_base + r;
            sc0[r] = (j0 + lo <= qq) ? s0[r] : -1e30f;
            sc1[r] = (j0 + 16 + lo <= qq) ? s1[r] : -1e30f;
        }
        // ---- row max across 16 cols (lanes sharing qd) ----
        float tmax[4];
#pragma unroll
        for (int r = 0; r < 4; r++) tmax[r] = fmaxf(sc0[r], sc1[r]);
#pragma unroll
        for (int off = 1; off < 16; off <<= 1)
#pragma unroll
            for (int r = 0; r < 4; r++)
                tmax[r] = fmaxf(tmax[r], __shfl_xor(tmax[r], off, 16));
        // ---- online softmax update ----
        float alpha[4], psum[4];
#pragma unroll
        for (int r = 0; r < 4; r++) {
            float mnew = fmaxf(mrow[r], tmax[r]);
            alpha[r] = exp2f(mrow[r] - mnew);
            mrow[r]  = mnew;
            sc0[r]   = exp2f(sc0[r] - mnew);
            sc1[r]   = exp2f(sc1[r] - mnew);
            psum[r]  = sc0[r] + sc1[r];
        }
#pragma unroll
        for (int off = 1; off < 16; off <<= 1)
#pragma unroll
            for (int r = 0; r < 4; r++)
                psum[r] += __shfl_xor(psum[r], off, 16);
#pragma unroll
        for (int r = 0; r < 4; r++) lrow[r] = lrow[r] * alpha[r] + psum[r];
#pragma unroll
        for (int c = 0; c < 4; c++)
#pragma unroll
            for (int r = 0; r < 4; r++) oacc[c][r] *= alpha[r];
        // ---- P: C-layout -> LDS -> A-layout ----
#pragma unroll
        for (int r = 0; r < 4; r++) {
            plds[qd * 4 + r][lo]      = (__bf16)sc0[r];
            plds[qd * 4 + r][16 + lo] = (__bf16)sc1[r];
        }
        __asm__ volatile("s_waitcnt lgkmcnt(0)" ::: "memory");
        bf16x8 pa = *(const bf16x8*)(&plds[lo][qd * 8]);
        // ---- O += P @ V ----
#pragma unroll
        for (int c = 0; c < 4; c++) {
            bf16x8 vb = *(const bf16x8*)(Vh + (size_t)(c * 16 + lo) * T_ + j0 + qd * 8);
            oacc[c] = MFMA16(pa, vb, oacc[c]);
        }
        // read of plds complete before next iter's writes (WAR fence)
        __asm__ volatile("s_waitcnt lgkmcnt(0)" ::: "memory");
    }

    // ---- normalize + store O as [B][T][H*64] bf16 ----
#pragma unroll
    for (int c = 0; c < 4; c++) {
#pragma unroll
        for (int r = 0; r < 4; r++) {
            float val = oacc[c][r] / lrow[r];
            size_t idx = ((size_t)b * T_ + (qrow_base + r)) * D_ + h * DH_ + c * 16 + lo;
            O[idx] = (__bf16)val;
        }
    }
}

// -------------------------------- launcher ---------------------------------

extern "C" void kernel_launch(void* const* d_in, const int* in_sizes, int n_in,
                              void* d_out, int out_size, void* d_ws, size_t ws_size,
                              hipStream_t stream) {
    const float* x      = (const float*)d_in[0];
    const float* w_attn = (const float*)d_in[1];
    const float* b_attn = (const float*)d_in[2];
    const float* w_proj = (const float*)d_in[3];
    const float* b_proj = (const float*)d_in[4];
    float* out = (float*)d_out;

    const size_t MB = (size_t)1 << 20;
    if (ws_size < 48 * MB) return;   // need 48 MB scratch

    char* ws = (char*)d_ws;
    __bf16* xb     = (__bf16*)(ws);              //  8 MB  [M][D]
    __bf16* wattnT = (__bf16*)(ws + 8 * MB);     //  6 MB  [3D][D]
    __bf16* wprojT = (__bf16*)(ws + 14 * MB);    //  2 MB  [D][D]
    __bf16* Qb     = (__bf16*)(ws + 16 * MB);    //  8 MB  [BH][T][64]
    __bf16* Kb     = (__bf16*)(ws + 24 * MB);    //  8 MB  [BH][T][64]
    __bf16* Vt     = (__bf16*)(ws + 32 * MB);    //  8 MB  [BH][64][T]
    __bf16* Ob     = (__bf16*)(ws + 40 * MB);    //  8 MB  [M][D]

    // 1. converts
    f32_to_bf16_kernel<<<(M_ * D_) / 1024, 256, 0, stream>>>(x, xb, M_ * D_);
    transpose_bf16_kernel<<<dim3(N1_ / 32, D_ / 32), dim3(32, 8), 0, stream>>>(
        w_attn, wattnT, D_, N1_);
    transpose_bf16_kernel<<<dim3(D_ / 32, D_ / 32), dim3(32, 8), 0, stream>>>(
        w_proj, wprojT, D_, D_);
    // 2. QKV GEMM -> Q(scaled)/K/Vt
    gemm_bt_kernel<0><<<dim3(N1_ / 128, M_ / 128), 256, 0, stream>>>(
        xb, wattnT, b_attn, nullptr, Qb, Kb, Vt, M_, N1_, D_);
    // 3. causal flash attention
    attn_kernel<<<dim3(T_ / 64, B_ * H_), 256, 0, stream>>>(Qb, Kb, Vt, Ob);
    // 4. output projection (fp32 + bias)
    gemm_bt_kernel<1><<<dim3(D_ / 128, M_ / 128), 256, 0, stream>>>(
        Ob, wprojT, b_proj, out, nullptr, nullptr, nullptr, M_, D_, D_);
}

// Round 5
// 281.488 us; speedup vs baseline: 1.5033x; 1.5033x over previous
//
#include <hip/hip_runtime.h>

// ---------------------------------------------------------------------------
// FlashAttention block: out = proj(causal_attn(qkv(x)))
// B=2, T=2048, D=1024, H=16, dhead=64.  All GEMMs + attention in bf16 MFMA
// (16x16x32), fp32 accumulate.  fp32 output.
// R5: double-buffered LDS staging (ping-pong) + prefetch in attn and gemm.
// R4 flaked on graph replay (fresh launches OK): suspected WAR window where
// LDS-DMA overwrote the buffer waves had just read, guarded only by barrier
// drains.  Dbuf removes that window (stage into other buffer) and halves
// barriers; explicit full waitcnt drain before every barrier.
// ---------------------------------------------------------------------------

#define B_   2
#define T_   2048
#define D_   1024
#define H_   16
#define DH_  64
#define M_   (B_ * T_)       // 4096
#define N1_  (3 * D_)        // 3072
// qscale folds 1/sqrt(dhead) and log2(e) so softmax uses native exp2
#define QSCALE (0.125f * 1.44269504088896340736f)

typedef __bf16 bf16x8 __attribute__((ext_vector_type(8)));
typedef __bf16 bf16x4 __attribute__((ext_vector_type(4)));
typedef float  f32x4  __attribute__((ext_vector_type(4)));

#define MFMA16(a, b, c) __builtin_amdgcn_mfma_f32_16x16x32_bf16((a), (b), (c), 0, 0, 0)

// async global->LDS, 16B per lane; LDS dest = base + lane*16 (wave-uniform base)
#define GLOAD16(gp, lp)                                                        \
    __builtin_amdgcn_global_load_lds(                                          \
        (const __attribute__((address_space(1))) void*)(gp),                   \
        (__attribute__((address_space(3))) void*)(lp), 16, 0, 0)

#define DRAIN_ALL() __asm__ volatile("s_waitcnt vmcnt(0) lgkmcnt(0)" ::: "memory")

// -------------------------------- converts ---------------------------------

__global__ void f32_to_bf16_kernel(const float* __restrict__ in,
                                   __bf16* __restrict__ out, int n) {
    int i = (blockIdx.x * blockDim.x + threadIdx.x) * 4;
    if (i + 3 < n) {
        float4 f = *(const float4*)(in + i);
        bf16x4 o;
        o[0] = (__bf16)f.x; o[1] = (__bf16)f.y; o[2] = (__bf16)f.z; o[3] = (__bf16)f.w;
        *(bf16x4*)(out + i) = o;
    }
}

// in: fp32 [R][C]  ->  out: bf16 [C][R]
__global__ void transpose_bf16_kernel(const float* __restrict__ in,
                                      __bf16* __restrict__ out, int R, int C) {
    __shared__ float tile[32][33];
    int tx = threadIdx.x;          // 0..31
    int ty = threadIdx.y;          // 0..7
    int c0 = blockIdx.x * 32;
    int r0 = blockIdx.y * 32;
#pragma unroll
    for (int i = 0; i < 4; i++)
        tile[ty + i * 8][tx] = in[(size_t)(r0 + ty + i * 8) * C + c0 + tx];
    __syncthreads();
#pragma unroll
    for (int i = 0; i < 4; i++)
        out[(size_t)(c0 + ty + i * 8) * R + r0 + tx] = (__bf16)tile[tx][ty + i * 8];
}

// ------------------------------- MFMA GEMM ---------------------------------
// C[M][N] = A[M][K] @ Bt[N][K]^T + bias.  128x128 tile, 256 threads (4 waves),
// wave covers 64x64 as 4x4 frags of 16x16, BK=32.  Double-buffered
// global_load_lds staging with next-tile prefetch; one barrier per K-step.
// EPI 0: scatter to Q (scaled), K, Vt (bf16).  EPI 1: fp32 out + bias.

template <int EPI>
__global__ __launch_bounds__(256) void gemm_bt_kernel(
    const __bf16* __restrict__ A, const __bf16* __restrict__ Bt,
    const float* __restrict__ bias, float* __restrict__ Cout,
    __bf16* __restrict__ Q, __bf16* __restrict__ Kb, __bf16* __restrict__ Vt,
    int M, int N, int K) {
    __shared__ __bf16 As[2][128 * 32];   // 2 x 8 KB, row-major [128][32]
    __shared__ __bf16 Bs[2][128 * 32];

    const int tid  = threadIdx.x;
    const int lane = tid & 63;
    const int wave = tid >> 6;
    const int lo   = lane & 15;
    const int qd   = lane >> 4;
    const int wm   = (wave >> 1) * 64;
    const int wn   = (wave & 1) * 64;
    const int m0   = blockIdx.y * 128;
    const int n0   = blockIdx.x * 128;

    // staging: chunk g=(wave*2+c)*64+lane -> LDS byte g*16; row=g>>2, col16=g&3
    const int g0  = wave * 128 + lane;
    const int g1  = g0 + 64;
    const __bf16* gA0 = A + (size_t)(m0 + (g0 >> 2)) * K + (g0 & 3) * 8;
    const __bf16* gA1 = A + (size_t)(m0 + (g1 >> 2)) * K + (g1 & 3) * 8;
    const __bf16* gB0 = Bt + (size_t)(n0 + (g0 >> 2)) * K + (g0 & 3) * 8;
    const __bf16* gB1 = Bt + (size_t)(n0 + (g1 >> 2)) * K + (g1 & 3) * 8;
    const int so0 = wave * 1024;         // elem offset of this wave's seg 0
    const int so1 = wave * 1024 + 512;   // seg 1

    f32x4 acc[4][4] = {};
    const int nk = K >> 5;

    // prologue: stage tile 0 into buffer 0
    GLOAD16(gA0, As[0] + so0);
    GLOAD16(gA1, As[0] + so1);
    GLOAD16(gB0, Bs[0] + so0);
    GLOAD16(gB1, Bs[0] + so1);
    DRAIN_ALL();
    __syncthreads();

    for (int kt = 0; kt < nk; kt++) {
        const int cur = kt & 1;
        if (kt + 1 < nk) {               // prefetch next tile into other buffer
            const int k0n = (kt + 1) << 5;
            GLOAD16(gA0 + k0n, As[1 - cur] + so0);
            GLOAD16(gA1 + k0n, As[1 - cur] + so1);
            GLOAD16(gB0 + k0n, Bs[1 - cur] + so0);
            GLOAD16(gB1 + k0n, Bs[1 - cur] + so1);
        }
        bf16x8 af[4], bfr[4];
#pragma unroll
        for (int i = 0; i < 4; i++)
            af[i] = *(const bf16x8*)(As[cur] + (wm + i * 16 + lo) * 32 + qd * 8);
#pragma unroll
        for (int j = 0; j < 4; j++)
            bfr[j] = *(const bf16x8*)(Bs[cur] + (wn + j * 16 + lo) * 32 + qd * 8);
#pragma unroll
        for (int i = 0; i < 4; i++)
#pragma unroll
            for (int j = 0; j < 4; j++)
                acc[i][j] = MFMA16(af[i], bfr[j], acc[i][j]);
        DRAIN_ALL();                     // prefetch landed + all LDS ops done
        __syncthreads();
    }

#pragma unroll
    for (int i = 0; i < 4; i++) {
#pragma unroll
        for (int j = 0; j < 4; j++) {
#pragma unroll
            for (int r = 0; r < 4; r++) {
                int gm = m0 + wm + i * 16 + qd * 4 + r;   // C/D row
                int gn = n0 + wn + j * 16 + lo;           // C/D col
                float v = acc[i][j][r] + bias[gn];
                if (EPI == 1) {
                    Cout[(size_t)gm * N + gn] = v;
                } else {
                    int which = gn >> 10;                 // 0=q 1=k 2=v
                    int bh = ((gm >> 11) << 4) + ((gn >> 6) & 15);
                    int dd = gn & 63;
                    int t  = gm & (T_ - 1);
                    if (which == 0)
                        Q[((size_t)bh * T_ + t) * DH_ + dd] = (__bf16)(v * QSCALE);
                    else if (which == 1)
                        Kb[((size_t)bh * T_ + t) * DH_ + dd] = (__bf16)v;
                    else
                        Vt[((size_t)bh * DH_ + dd) * T_ + t] = (__bf16)v;
                }
            }
        }
    }
}

// ---------------------------- flash attention ------------------------------
// Block = 64 q-rows (4 waves x 16), all waves share 64-key K/V LDS tiles.
// Double-buffered: prefetch tile t+1 while computing tile t; one barrier per
// tile.  Rows are 128B; column-chunk XOR-swizzled by (row&7) so frag
// ds_read_b128 spreads across banks.  Per-lane causal mask only on diagonal
// tile (gate: j0+63 > q0, wave-uniform).  Heavy-first block order.

__global__ __launch_bounds__(256) void attn_kernel(
    const __bf16* __restrict__ Q,   // [BH][T][64], pre-scaled
    const __bf16* __restrict__ Kb,  // [BH][T][64]
    const __bf16* __restrict__ Vt,  // [BH][64][T]
    __bf16* __restrict__ O) {       // [B][T][H*64]
    __shared__ __bf16 Ks[2][64 * 64];     // [key][d]  2 x 8 KB, swizzled
    __shared__ __bf16 Vs[2][64 * 64];     // [d][key]  2 x 8 KB, swizzled
    __shared__ __bf16 Ps[4][16][72];      // per-wave P transpose buffer

    const int tid  = threadIdx.x;
    const int wave = tid >> 6;
    const int lane = tid & 63;
    const int lo   = lane & 15;
    const int qd   = lane >> 4;
    const int xblk = gridDim.x - 1 - blockIdx.x;   // heavy blocks first
    const int bh   = blockIdx.y;
    const int b    = bh >> 4;
    const int h    = bh & 15;
    const int q0b  = xblk * 64;
    const int q0   = q0b + wave * 16;

    const __bf16* Qh = Q + (size_t)bh * T_ * DH_;
    const __bf16* Kh = Kb + (size_t)bh * T_ * DH_;
    const __bf16* Vh = Vt + (size_t)bh * DH_ * T_;

    // Q A-frags: lane holds Q[q0+lo][chunk*32 + qd*8 + j]
    bf16x8 qa0 = *(const bf16x8*)(Qh + (size_t)(q0 + lo) * DH_ + qd * 8);
    bf16x8 qa1 = *(const bf16x8*)(Qh + (size_t)(q0 + lo) * DH_ + 32 + qd * 8);

    // staging decode: chunk g=(wave*2+c)*64+lane -> LDS byte g*16;
    // row=g>>3, cc_lds=g&7, global cc = cc_lds ^ (row&7)
    const int g0  = wave * 128 + lane;
    const int g1  = g0 + 64;
    const int r0s = g0 >> 3, c0s = (g0 & 7) ^ (r0s & 7);
    const int r1s = g1 >> 3, c1s = (g1 & 7) ^ (r1s & 7);
    const int so0 = wave * 1024;         // elem offset of this wave's seg 0
    const int so1 = wave * 1024 + 512;

    f32x4 oacc[4] = {};
    float mrow[4], lrow[4];
#pragma unroll
    for (int r = 0; r < 4; r++) { mrow[r] = -1e30f; lrow[r] = 0.0f; }

    const int qrow = q0 + qd * 4;   // + r
    const int ntile = (q0b >> 6) + 1;

    // prologue: stage tile 0 into buffer 0
    GLOAD16(Kh + (size_t)r0s * DH_ + c0s * 8, Ks[0] + so0);
    GLOAD16(Kh + (size_t)r1s * DH_ + c1s * 8, Ks[0] + so1);
    GLOAD16(Vh + (size_t)r0s * T_ + c0s * 8, Vs[0] + so0);
    GLOAD16(Vh + (size_t)r1s * T_ + c1s * 8, Vs[0] + so1);
    DRAIN_ALL();
    __syncthreads();

    for (int t = 0; t < ntile; t++) {
        const int j0  = t << 6;
        const int cur = t & 1;
        if (t + 1 < ntile) {             // prefetch next K/V tile
            const int j0n = j0 + 64;
            GLOAD16(Kh + (size_t)(j0n + r0s) * DH_ + c0s * 8, Ks[1 - cur] + so0);
            GLOAD16(Kh + (size_t)(j0n + r1s) * DH_ + c1s * 8, Ks[1 - cur] + so1);
            GLOAD16(Vh + (size_t)r0s * T_ + j0n + c0s * 8, Vs[1 - cur] + so0);
            GLOAD16(Vh + (size_t)r1s * T_ + j0n + c1s * 8, Vs[1 - cur] + so1);
        }

        // ---- S = Q @ K^T, 64 keys as 4 col-groups of 16 ----
        f32x4 s[4] = {};
#pragma unroll
        for (int g = 0; g < 4; g++) {
            const int row = g * 16 + lo;
            const __bf16* kr = Ks[cur] + row * 64;
            bf16x8 kb0 = *(const bf16x8*)(kr + ((qd ^ (row & 7)) << 3));
            bf16x8 kb1 = *(const bf16x8*)(kr + (((4 + qd) ^ (row & 7)) << 3));
            s[g] = MFMA16(qa0, kb0, s[g]);
            s[g] = MFMA16(qa1, kb1, s[g]);
        }

        // ---- causal mask (diagonal tile only; wave-uniform gate) ----
        if (j0 + 63 > q0) {
#pragma unroll
            for (int g = 0; g < 4; g++) {
                const int col = j0 + g * 16 + lo;
#pragma unroll
                for (int r = 0; r < 4; r++)
                    s[g][r] = (col <= qrow + r) ? s[g][r] : -1e30f;
            }
        }

        // ---- online softmax over 64 cols ----
        float tmax[4];
#pragma unroll
        for (int r = 0; r < 4; r++)
            tmax[r] = fmaxf(fmaxf(s[0][r], s[1][r]), fmaxf(s[2][r], s[3][r]));
#pragma unroll
        for (int off = 1; off < 16; off <<= 1)
#pragma unroll
            for (int r = 0; r < 4; r++)
                tmax[r] = fmaxf(tmax[r], __shfl_xor(tmax[r], off, 16));
        float alpha[4];
#pragma unroll
        for (int r = 0; r < 4; r++) {
            float mnew = fmaxf(mrow[r], tmax[r]);
            alpha[r] = exp2f(mrow[r] - mnew);
            mrow[r]  = mnew;
        }
        float p[4][4], psum[4];
#pragma unroll
        for (int g = 0; g < 4; g++)
#pragma unroll
            for (int r = 0; r < 4; r++)
                p[g][r] = exp2f(s[g][r] - mrow[r]);
#pragma unroll
        for (int r = 0; r < 4; r++)
            psum[r] = (p[0][r] + p[1][r]) + (p[2][r] + p[3][r]);
#pragma unroll
        for (int off = 1; off < 16; off <<= 1)
#pragma unroll
            for (int r = 0; r < 4; r++)
                psum[r] += __shfl_xor(psum[r], off, 16);
#pragma unroll
        for (int r = 0; r < 4; r++) lrow[r] = lrow[r] * alpha[r] + psum[r];
#pragma unroll
        for (int c = 0; c < 4; c++)
#pragma unroll
            for (int r = 0; r < 4; r++) oacc[c][r] *= alpha[r];

        // ---- P: C-layout -> per-wave LDS -> A-layout ----
        // (within-wave hazard only; LDS ops in-order per wave + lgkm fence)
#pragma unroll
        for (int g = 0; g < 4; g++)
#pragma unroll
            for (int r = 0; r < 4; r++)
                Ps[wave][qd * 4 + r][g * 16 + lo] = (__bf16)p[g][r];
        __asm__ volatile("s_waitcnt lgkmcnt(0)" ::: "memory");
        bf16x8 pa0 = *(const bf16x8*)(&Ps[wave][lo][qd * 8]);
        bf16x8 pa1 = *(const bf16x8*)(&Ps[wave][lo][32 + qd * 8]);

        // ---- O += P @ V ----
#pragma unroll
        for (int c = 0; c < 4; c++) {
            const int row = c * 16 + lo;
            const __bf16* vr = Vs[cur] + row * 64;
            bf16x8 vb0 = *(const bf16x8*)(vr + ((qd ^ (row & 7)) << 3));
            bf16x8 vb1 = *(const bf16x8*)(vr + (((4 + qd) ^ (row & 7)) << 3));
            oacc[c] = MFMA16(pa0, vb0, oacc[c]);
            oacc[c] = MFMA16(pa1, vb1, oacc[c]);
        }

        DRAIN_ALL();                     // prefetch landed + all LDS ops done
        __syncthreads();
    }

    // ---- normalize + store O as [B][T][H*64] bf16 ----
    float inv[4];
#pragma unroll
    for (int r = 0; r < 4; r++) inv[r] = 1.0f / lrow[r];
#pragma unroll
    for (int c = 0; c < 4; c++) {
#pragma unroll
        for (int r = 0; r < 4; r++) {
            float val = oacc[c][r] * inv[r];
            size_t idx = ((size_t)b * T_ + (qrow + r)) * D_ + h * DH_ + c * 16 + lo;
            O[idx] = (__bf16)val;
        }
    }
}

// -------------------------------- launcher ---------------------------------

extern "C" void kernel_launch(void* const* d_in, const int* in_sizes, int n_in,
                              void* d_out, int out_size, void* d_ws, size_t ws_size,
                              hipStream_t stream) {
    const float* x      = (const float*)d_in[0];
    const float* w_attn = (const float*)d_in[1];
    const float* b_attn = (const float*)d_in[2];
    const float* w_proj = (const float*)d_in[3];
    const float* b_proj = (const float*)d_in[4];
    float* out = (float*)d_out;

    const size_t MB = (size_t)1 << 20;
    if (ws_size < 48 * MB) return;   // need 48 MB scratch

    char* ws = (char*)d_ws;
    __bf16* xb     = (__bf16*)(ws);              //  8 MB  [M][D]
    __bf16* wattnT = (__bf16*)(ws + 8 * MB);     //  6 MB  [3D][D]
    __bf16* wprojT = (__bf16*)(ws + 14 * MB);    //  2 MB  [D][D]
    __bf16* Qb     = (__bf16*)(ws + 16 * MB);    //  8 MB  [BH][T][64]
    __bf16* Kb     = (__bf16*)(ws + 24 * MB);    //  8 MB  [BH][T][64]
    __bf16* Vt     = (__bf16*)(ws + 32 * MB);    //  8 MB  [BH][64][T]
    __bf16* Ob     = (__bf16*)(ws + 40 * MB);    //  8 MB  [M][D]

    // 1. converts
    f32_to_bf16_kernel<<<(M_ * D_) / 1024, 256, 0, stream>>>(x, xb, M_ * D_);
    transpose_bf16_kernel<<<dim3(N1_ / 32, D_ / 32), dim3(32, 8), 0, stream>>>(
        w_attn, wattnT, D_, N1_);
    transpose_bf16_kernel<<<dim3(D_ / 32, D_ / 32), dim3(32, 8), 0, stream>>>(
        w_proj, wprojT, D_, D_);
    // 2. QKV GEMM -> Q(scaled)/K/Vt
    gemm_bt_kernel<0><<<dim3(N1_ / 128, M_ / 128), 256, 0, stream>>>(
        xb, wattnT, b_attn, nullptr, Qb, Kb, Vt, M_, N1_, D_);
    // 3. causal flash attention (shared K/V tiles, dbuf, heavy-first)
    attn_kernel<<<dim3(T_ / 64, B_ * H_), 256, 0, stream>>>(Qb, Kb, Vt, Ob);
    // 4. output projection (fp32 + bias)
    gemm_bt_kernel<1><<<dim3(D_ / 128, M_ / 128), 256, 0, stream>>>(
        Ob, wprojT, b_proj, out, nullptr, nullptr, nullptr, M_, D_, D_);
}

// Round 6
// 269.065 us; speedup vs baseline: 1.5728x; 1.0462x over previous
//
#include <hip/hip_runtime.h>

// ---------------------------------------------------------------------------
// FlashAttention block: out = proj(causal_attn(qkv(x)))
// B=2, T=2048, D=1024, H=16, dhead=64.  All GEMMs + attention in bf16 MFMA
// (16x16x32), fp32 accumulate.  fp32 output.
// R6: attn 32 q-rows/wave (128/block, halves tile-iters), XCD-aware block
// mapping (4 heads per XCD L2), gemm<1> 64-row tiles (2 blocks/CU).
// ---------------------------------------------------------------------------

#define B_   2
#define T_   2048
#define D_   1024
#define H_   16
#define DH_  64
#define M_   (B_ * T_)       // 4096
#define N1_  (3 * D_)        // 3072
// qscale folds 1/sqrt(dhead) and log2(e) so softmax uses native exp2
#define QSCALE (0.125f * 1.44269504088896340736f)

typedef __bf16 bf16x8 __attribute__((ext_vector_type(8)));
typedef __bf16 bf16x4 __attribute__((ext_vector_type(4)));
typedef float  f32x4  __attribute__((ext_vector_type(4)));

#define MFMA16(a, b, c) __builtin_amdgcn_mfma_f32_16x16x32_bf16((a), (b), (c), 0, 0, 0)

// async global->LDS, 16B per lane; LDS dest = base + lane*16 (wave-uniform base)
#define GLOAD16(gp, lp)                                                        \
    __builtin_amdgcn_global_load_lds(                                          \
        (const __attribute__((address_space(1))) void*)(gp),                   \
        (__attribute__((address_space(3))) void*)(lp), 16, 0, 0)

#define DRAIN_ALL() __asm__ volatile("s_waitcnt vmcnt(0) lgkmcnt(0)" ::: "memory")

// -------------------------------- converts ---------------------------------

__global__ void f32_to_bf16_kernel(const float* __restrict__ in,
                                   __bf16* __restrict__ out, int n) {
    int i = (blockIdx.x * blockDim.x + threadIdx.x) * 4;
    if (i + 3 < n) {
        float4 f = *(const float4*)(in + i);
        bf16x4 o;
        o[0] = (__bf16)f.x; o[1] = (__bf16)f.y; o[2] = (__bf16)f.z; o[3] = (__bf16)f.w;
        *(bf16x4*)(out + i) = o;
    }
}

// in: fp32 [R][C]  ->  out: bf16 [C][R]
__global__ void transpose_bf16_kernel(const float* __restrict__ in,
                                      __bf16* __restrict__ out, int R, int C) {
    __shared__ float tile[32][33];
    int tx = threadIdx.x;          // 0..31
    int ty = threadIdx.y;          // 0..7
    int c0 = blockIdx.x * 32;
    int r0 = blockIdx.y * 32;
#pragma unroll
    for (int i = 0; i < 4; i++)
        tile[ty + i * 8][tx] = in[(size_t)(r0 + ty + i * 8) * C + c0 + tx];
    __syncthreads();
#pragma unroll
    for (int i = 0; i < 4; i++)
        out[(size_t)(c0 + ty + i * 8) * R + r0 + tx] = (__bf16)tile[tx][ty + i * 8];
}

// ------------------------------- MFMA GEMM ---------------------------------
// C[M][N] = A[M][K] @ Bt[N][K]^T + bias.  TM x 128 tile, 256 threads (4
// waves), wave covers (TM/2) x 64 as (TM/32)x4 frags of 16x16, BK=32.
// Double-buffered global_load_lds staging with next-tile prefetch.
// EPI 0: scatter to Q (scaled), K, Vt (bf16).  EPI 1: fp32 out + bias.

template <int EPI, int TM>
__global__ __launch_bounds__(256) void gemm_bt_kernel(
    const __bf16* __restrict__ A, const __bf16* __restrict__ Bt,
    const float* __restrict__ bias, float* __restrict__ Cout,
    __bf16* __restrict__ Q, __bf16* __restrict__ Kb, __bf16* __restrict__ Vt,
    int M, int N, int K) {
    constexpr int MI  = TM / 32;          // m-frags per wave (4 or 2)
    constexpr int WM  = MI * 16;          // rows per wave (64 or 32)
    constexpr int ACH = TM / 64;          // A-chunk rounds (2 or 1)
    __shared__ __bf16 As[2][TM * 32];     // row-major [TM][32]
    __shared__ __bf16 Bs[2][128 * 32];

    const int tid  = threadIdx.x;
    const int lane = tid & 63;
    const int wave = tid >> 6;
    const int lo   = lane & 15;
    const int qd   = lane >> 4;
    const int wm   = (wave >> 1) * WM;
    const int wn   = (wave & 1) * 64;
    const int m0   = blockIdx.y * TM;
    const int n0   = blockIdx.x * 128;

    // chunk g (16B) -> LDS byte g*16; global row g>>2, k-off (g&3)*8
    const __bf16* gA[ACH];
    const __bf16* gB[2];
#pragma unroll
    for (int c = 0; c < ACH; c++) {
        int g = tid + 256 * c;
        gA[c] = A + (size_t)(m0 + (g >> 2)) * K + (g & 3) * 8;
    }
#pragma unroll
    for (int c = 0; c < 2; c++) {
        int g = tid + 256 * c;
        gB[c] = Bt + (size_t)(n0 + (g >> 2)) * K + (g & 3) * 8;
    }

    f32x4 acc[MI][4] = {};
    const int nk = K >> 5;

    // prologue: stage tile 0 into buffer 0
#pragma unroll
    for (int c = 0; c < ACH; c++)
        GLOAD16(gA[c], (__bf16*)As[0] + (tid + 256 * c) * 8);
#pragma unroll
    for (int c = 0; c < 2; c++)
        GLOAD16(gB[c], (__bf16*)Bs[0] + (tid + 256 * c) * 8);
    DRAIN_ALL();
    __syncthreads();

    for (int kt = 0; kt < nk; kt++) {
        const int cur = kt & 1;
        if (kt + 1 < nk) {               // prefetch next tile into other buffer
            const int k0n = (kt + 1) << 5;
#pragma unroll
            for (int c = 0; c < ACH; c++)
                GLOAD16(gA[c] + k0n, (__bf16*)As[1 - cur] + (tid + 256 * c) * 8);
#pragma unroll
            for (int c = 0; c < 2; c++)
                GLOAD16(gB[c] + k0n, (__bf16*)Bs[1 - cur] + (tid + 256 * c) * 8);
        }
        bf16x8 af[MI], bfr[4];
#pragma unroll
        for (int i = 0; i < MI; i++)
            af[i] = *(const bf16x8*)(As[cur] + (wm + i * 16 + lo) * 32 + qd * 8);
#pragma unroll
        for (int j = 0; j < 4; j++)
            bfr[j] = *(const bf16x8*)(Bs[cur] + (wn + j * 16 + lo) * 32 + qd * 8);
#pragma unroll
        for (int i = 0; i < MI; i++)
#pragma unroll
            for (int j = 0; j < 4; j++)
                acc[i][j] = MFMA16(af[i], bfr[j], acc[i][j]);
        DRAIN_ALL();                     // prefetch landed + all LDS ops done
        __syncthreads();
    }

#pragma unroll
    for (int i = 0; i < MI; i++) {
#pragma unroll
        for (int j = 0; j < 4; j++) {
#pragma unroll
            for (int r = 0; r < 4; r++) {
                int gm = m0 + wm + i * 16 + qd * 4 + r;   // C/D row
                int gn = n0 + wn + j * 16 + lo;           // C/D col
                float v = acc[i][j][r] + bias[gn];
                if (EPI == 1) {
                    Cout[(size_t)gm * N + gn] = v;
                } else {
                    int which = gn >> 10;                 // 0=q 1=k 2=v
                    int bh = ((gm >> 11) << 4) + ((gn >> 6) & 15);
                    int dd = gn & 63;
                    int t  = gm & (T_ - 1);
                    if (which == 0)
                        Q[((size_t)bh * T_ + t) * DH_ + dd] = (__bf16)(v * QSCALE);
                    else if (which == 1)
                        Kb[((size_t)bh * T_ + t) * DH_ + dd] = (__bf16)v;
                    else
                        Vt[((size_t)bh * DH_ + dd) * T_ + t] = (__bf16)v;
                }
            }
        }
    }
}

// ---------------------------- flash attention ------------------------------
// Block = 128 q-rows (4 waves x 32), sharing 64-key K/V LDS tiles (dbuf +
// prefetch, one barrier/tile).  Wave holds 2 row-groups of 16; 32 MFMA per
// tile-iter.  K/V rows 128B, column-chunk XOR-swizzled by (row&7).
// Causal mask per-lane only on tiles with j0+63 > q0 (wave-uniform gate).
// XCD-aware linear block mapping: 4 heads pinned per XCD, heavy-first.

__global__ __launch_bounds__(256) void attn_kernel(
    const __bf16* __restrict__ Q,   // [BH][T][64], pre-scaled
    const __bf16* __restrict__ Kb,  // [BH][T][64]
    const __bf16* __restrict__ Vt,  // [BH][64][T]
    __bf16* __restrict__ O) {       // [B][T][H*64]
    __shared__ __bf16 Ks[2][64 * 64];     // [key][d]  2 x 8 KB, swizzled
    __shared__ __bf16 Vs[2][64 * 64];     // [d][key]  2 x 8 KB, swizzled
    __shared__ __bf16 Ps[4][2][16 * 72];  // per-wave, per-rowgroup P buffer

    const int tid  = threadIdx.x;
    const int wave = tid >> 6;
    const int lane = tid & 63;
    const int lo   = lane & 15;
    const int qd   = lane >> 4;

    // XCD-aware: linear id L -> XCD L&7 (round-robin heuristic); 4 heads per
    // XCD so each XCD L2 holds ~2 MB of K/V; heavy tiles dispatched first.
    const int L    = blockIdx.x;          // 0..511
    const int grp  = L >> 3;              // 0..63
    const int bh   = (L & 7) * 4 + (grp >> 4);
    const int xblk = 15 - (grp & 15);     // heavy first
    const int b    = bh >> 4;
    const int h    = bh & 15;
    const int q0b  = xblk * 128;
    const int q0   = q0b + wave * 32;

    const __bf16* Qh = Q + (size_t)bh * T_ * DH_;
    const __bf16* Kh = Kb + (size_t)bh * T_ * DH_;
    const __bf16* Vh = Vt + (size_t)bh * DH_ * T_;

    // Q A-frags per row-group: lane holds Q[q0+rg*16+lo][half*32 + qd*8 + j]
    bf16x8 qa[2][2];
#pragma unroll
    for (int rg = 0; rg < 2; rg++) {
        const __bf16* qr = Qh + (size_t)(q0 + rg * 16 + lo) * DH_;
        qa[rg][0] = *(const bf16x8*)(qr + qd * 8);
        qa[rg][1] = *(const bf16x8*)(qr + 32 + qd * 8);
    }

    // staging decode: chunk g -> LDS byte g*16; row=g>>3, cc_lds=g&7,
    // global cc = cc_lds ^ (row&7)
    const int g0  = wave * 128 + lane;
    const int g1  = g0 + 64;
    const int r0s = g0 >> 3, c0s = (g0 & 7) ^ (r0s & 7);
    const int r1s = g1 >> 3, c1s = (g1 & 7) ^ (r1s & 7);
    const int so0 = wave * 1024;
    const int so1 = wave * 1024 + 512;

    f32x4 oacc[2][4] = {};
    float mrow[2][4], lrow[2][4];
#pragma unroll
    for (int rg = 0; rg < 2; rg++)
#pragma unroll
        for (int r = 0; r < 4; r++) { mrow[rg][r] = -1e30f; lrow[rg][r] = 0.0f; }

    const int qrb[2] = {q0 + qd * 4, q0 + 16 + qd * 4};
    const int ntile = (q0b >> 6) + 2;     // keys 0 .. q0b+127

    // prologue: stage tile 0 into buffer 0
    GLOAD16(Kh + (size_t)r0s * DH_ + c0s * 8, Ks[0] + so0);
    GLOAD16(Kh + (size_t)r1s * DH_ + c1s * 8, Ks[0] + so1);
    GLOAD16(Vh + (size_t)r0s * T_ + c0s * 8, Vs[0] + so0);
    GLOAD16(Vh + (size_t)r1s * T_ + c1s * 8, Vs[0] + so1);
    DRAIN_ALL();
    __syncthreads();

    for (int t = 0; t < ntile; t++) {
        const int j0  = t << 6;
        const int cur = t & 1;
        if (t + 1 < ntile) {             // prefetch next K/V tile
            const int j0n = j0 + 64;
            GLOAD16(Kh + (size_t)(j0n + r0s) * DH_ + c0s * 8, Ks[1 - cur] + so0);
            GLOAD16(Kh + (size_t)(j0n + r1s) * DH_ + c1s * 8, Ks[1 - cur] + so1);
            GLOAD16(Vh + (size_t)r0s * T_ + j0n + c0s * 8, Vs[1 - cur] + so0);
            GLOAD16(Vh + (size_t)r1s * T_ + j0n + c1s * 8, Vs[1 - cur] + so1);
        }

        // ---- S = Q @ K^T, 64 keys x 2 row-groups ----
        f32x4 s[2][4] = {};
#pragma unroll
        for (int g = 0; g < 4; g++) {
            const int row = g * 16 + lo;
            const __bf16* kr = Ks[cur] + row * 64;
            bf16x8 kb0 = *(const bf16x8*)(kr + ((qd ^ (row & 7)) << 3));
            bf16x8 kb1 = *(const bf16x8*)(kr + (((4 + qd) ^ (row & 7)) << 3));
#pragma unroll
            for (int rg = 0; rg < 2; rg++) {
                s[rg][g] = MFMA16(qa[rg][0], kb0, s[rg][g]);
                s[rg][g] = MFMA16(qa[rg][1], kb1, s[rg][g]);
            }
        }

        // ---- causal mask (tiles overlapping/above wave rows; uniform gate) --
        if (j0 + 63 > q0) {
#pragma unroll
            for (int g = 0; g < 4; g++) {
                const int col = j0 + g * 16 + lo;
#pragma unroll
                for (int rg = 0; rg < 2; rg++)
#pragma unroll
                    for (int r = 0; r < 4; r++)
                        s[rg][g][r] = (col <= qrb[rg] + r) ? s[rg][g][r] : -1e30f;
            }
        }

        // ---- online softmax over 64 cols, both row-groups ----
        float tmax[2][4];
#pragma unroll
        for (int rg = 0; rg < 2; rg++)
#pragma unroll
            for (int r = 0; r < 4; r++)
                tmax[rg][r] = fmaxf(fmaxf(s[rg][0][r], s[rg][1][r]),
                                    fmaxf(s[rg][2][r], s[rg][3][r]));
#pragma unroll
        for (int off = 1; off < 16; off <<= 1)
#pragma unroll
            for (int rg = 0; rg < 2; rg++)
#pragma unroll
                for (int r = 0; r < 4; r++)
                    tmax[rg][r] = fmaxf(tmax[rg][r], __shfl_xor(tmax[rg][r], off, 16));
        float alpha[2][4];
#pragma unroll
        for (int rg = 0; rg < 2; rg++)
#pragma unroll
            for (int r = 0; r < 4; r++) {
                float mnew = fmaxf(mrow[rg][r], tmax[rg][r]);
                alpha[rg][r] = exp2f(mrow[rg][r] - mnew);
                mrow[rg][r]  = mnew;
            }
        float p[2][4][4], psum[2][4];
#pragma unroll
        for (int rg = 0; rg < 2; rg++)
#pragma unroll
            for (int g = 0; g < 4; g++)
#pragma unroll
                for (int r = 0; r < 4; r++)
                    p[rg][g][r] = exp2f(s[rg][g][r] - mrow[rg][r]);
#pragma unroll
        for (int rg = 0; rg < 2; rg++)
#pragma unroll
            for (int r = 0; r < 4; r++)
                psum[rg][r] = (p[rg][0][r] + p[rg][1][r]) + (p[rg][2][r] + p[rg][3][r]);
#pragma unroll
        for (int off = 1; off < 16; off <<= 1)
#pragma unroll
            for (int rg = 0; rg < 2; rg++)
#pragma unroll
                for (int r = 0; r < 4; r++)
                    psum[rg][r] += __shfl_xor(psum[rg][r], off, 16);
#pragma unroll
        for (int rg = 0; rg < 2; rg++)
#pragma unroll
            for (int r = 0; r < 4; r++)
                lrow[rg][r] = lrow[rg][r] * alpha[rg][r] + psum[rg][r];
#pragma unroll
        for (int rg = 0; rg < 2; rg++)
#pragma unroll
            for (int c = 0; c < 4; c++)
#pragma unroll
                for (int r = 0; r < 4; r++) oacc[rg][c][r] *= alpha[rg][r];

        // ---- P: C-layout -> per-wave LDS -> A-layout (both row-groups) ----
#pragma unroll
        for (int rg = 0; rg < 2; rg++)
#pragma unroll
            for (int g = 0; g < 4; g++)
#pragma unroll
                for (int r = 0; r < 4; r++)
                    Ps[wave][rg][(qd * 4 + r) * 72 + g * 16 + lo] = (__bf16)p[rg][g][r];
        __asm__ volatile("s_waitcnt lgkmcnt(0)" ::: "memory");
        bf16x8 pa[2][2];
#pragma unroll
        for (int rg = 0; rg < 2; rg++) {
            pa[rg][0] = *(const bf16x8*)(&Ps[wave][rg][lo * 72 + qd * 8]);
            pa[rg][1] = *(const bf16x8*)(&Ps[wave][rg][lo * 72 + 32 + qd * 8]);
        }

        // ---- O += P @ V ----
#pragma unroll
        for (int c = 0; c < 4; c++) {
            const int row = c * 16 + lo;
            const __bf16* vr = Vs[cur] + row * 64;
            bf16x8 vb0 = *(const bf16x8*)(vr + ((qd ^ (row & 7)) << 3));
            bf16x8 vb1 = *(const bf16x8*)(vr + (((4 + qd) ^ (row & 7)) << 3));
#pragma unroll
            for (int rg = 0; rg < 2; rg++) {
                oacc[rg][c] = MFMA16(pa[rg][0], vb0, oacc[rg][c]);
                oacc[rg][c] = MFMA16(pa[rg][1], vb1, oacc[rg][c]);
            }
        }

        DRAIN_ALL();                     // prefetch landed + all LDS ops done
        __syncthreads();
    }

    // ---- normalize + store O as [B][T][H*64] bf16 ----
#pragma unroll
    for (int rg = 0; rg < 2; rg++) {
        float inv[4];
#pragma unroll
        for (int r = 0; r < 4; r++) inv[r] = 1.0f / lrow[rg][r];
#pragma unroll
        for (int c = 0; c < 4; c++) {
#pragma unroll
            for (int r = 0; r < 4; r++) {
                float val = oacc[rg][c][r] * inv[r];
                size_t idx = ((size_t)b * T_ + (qrb[rg] + r)) * D_ + h * DH_ + c * 16 + lo;
                O[idx] = (__bf16)val;
            }
        }
    }
}

// -------------------------------- launcher ---------------------------------

extern "C" void kernel_launch(void* const* d_in, const int* in_sizes, int n_in,
                              void* d_out, int out_size, void* d_ws, size_t ws_size,
                              hipStream_t stream) {
    const float* x      = (const float*)d_in[0];
    const float* w_attn = (const float*)d_in[1];
    const float* b_attn = (const float*)d_in[2];
    const float* w_proj = (const float*)d_in[3];
    const float* b_proj = (const float*)d_in[4];
    float* out = (float*)d_out;

    const size_t MB = (size_t)1 << 20;
    if (ws_size < 48 * MB) return;   // need 48 MB scratch

    char* ws = (char*)d_ws;
    __bf16* xb     = (__bf16*)(ws);              //  8 MB  [M][D]
    __bf16* wattnT = (__bf16*)(ws + 8 * MB);     //  6 MB  [3D][D]
    __bf16* wprojT = (__bf16*)(ws + 14 * MB);    //  2 MB  [D][D]
    __bf16* Qb     = (__bf16*)(ws + 16 * MB);    //  8 MB  [BH][T][64]
    __bf16* Kb     = (__bf16*)(ws + 24 * MB);    //  8 MB  [BH][T][64]
    __bf16* Vt     = (__bf16*)(ws + 32 * MB);    //  8 MB  [BH][64][T]
    __bf16* Ob     = (__bf16*)(ws + 40 * MB);    //  8 MB  [M][D]

    // 1. converts
    f32_to_bf16_kernel<<<(M_ * D_) / 1024, 256, 0, stream>>>(x, xb, M_ * D_);
    transpose_bf16_kernel<<<dim3(N1_ / 32, D_ / 32), dim3(32, 8), 0, stream>>>(
        w_attn, wattnT, D_, N1_);
    transpose_bf16_kernel<<<dim3(D_ / 32, D_ / 32), dim3(32, 8), 0, stream>>>(
        w_proj, wprojT, D_, D_);
    // 2. QKV GEMM -> Q(scaled)/K/Vt
    gemm_bt_kernel<0, 128><<<dim3(N1_ / 128, M_ / 128), 256, 0, stream>>>(
        xb, wattnT, b_attn, nullptr, Qb, Kb, Vt, M_, N1_, D_);
    // 3. causal flash attention (128-row blocks, XCD-pinned heads)
    attn_kernel<<<dim3((T_ / 128) * B_ * H_), 256, 0, stream>>>(Qb, Kb, Vt, Ob);
    // 4. output projection (fp32 + bias), 64-row tiles for 2 blocks/CU
    gemm_bt_kernel<1, 64><<<dim3(D_ / 128, M_ / 64), 256, 0, stream>>>(
        Ob, wprojT, b_proj, out, nullptr, nullptr, nullptr, M_, D_, D_);
}

// Round 7
// 197.457 us; speedup vs baseline: 2.1431x; 1.3627x over previous
//
#include <hip/hip_runtime.h>

// ---------------------------------------------------------------------------
// FlashAttention block: out = proj(causal_attn(qkv(x)))
// B=2, T=2048, D=1024, H=16, dhead=64.  All GEMMs + attention in bf16 MFMA
// (16x16x32), fp32 accumulate.  fp32 output.
// R7: attn softmax rework (shared per-wave max, MFMA ones-trick row sums,
// uniform skip-rescale) + snake-balanced persistent 768-block schedule.
// ---------------------------------------------------------------------------

#define B_   2
#define T_   2048
#define D_   1024
#define H_   16
#define DH_  64
#define M_   (B_ * T_)       // 4096
#define N1_  (3 * D_)        // 3072
// qscale folds 1/sqrt(dhead) and log2(e) so softmax uses native exp2
#define QSCALE (0.125f * 1.44269504088896340736f)

typedef __bf16 bf16x8 __attribute__((ext_vector_type(8)));
typedef __bf16 bf16x4 __attribute__((ext_vector_type(4)));
typedef float  f32x4  __attribute__((ext_vector_type(4)));

#define MFMA16(a, b, c) __builtin_amdgcn_mfma_f32_16x16x32_bf16((a), (b), (c), 0, 0, 0)

// async global->LDS, 16B per lane; LDS dest = base + lane*16 (wave-uniform base)
#define GLOAD16(gp, lp)                                                        \
    __builtin_amdgcn_global_load_lds(                                          \
        (const __attribute__((address_space(1))) void*)(gp),                   \
        (__attribute__((address_space(3))) void*)(lp), 16, 0, 0)

#define DRAIN_ALL() __asm__ volatile("s_waitcnt vmcnt(0) lgkmcnt(0)" ::: "memory")

// -------------------------------- converts ---------------------------------

__global__ void f32_to_bf16_kernel(const float* __restrict__ in,
                                   __bf16* __restrict__ out, int n) {
    int i = (blockIdx.x * blockDim.x + threadIdx.x) * 4;
    if (i + 3 < n) {
        float4 f = *(const float4*)(in + i);
        bf16x4 o;
        o[0] = (__bf16)f.x; o[1] = (__bf16)f.y; o[2] = (__bf16)f.z; o[3] = (__bf16)f.w;
        *(bf16x4*)(out + i) = o;
    }
}

// in: fp32 [R][C]  ->  out: bf16 [C][R]
__global__ void transpose_bf16_kernel(const float* __restrict__ in,
                                      __bf16* __restrict__ out, int R, int C) {
    __shared__ float tile[32][33];
    int tx = threadIdx.x;          // 0..31
    int ty = threadIdx.y;          // 0..7
    int c0 = blockIdx.x * 32;
    int r0 = blockIdx.y * 32;
#pragma unroll
    for (int i = 0; i < 4; i++)
        tile[ty + i * 8][tx] = in[(size_t)(r0 + ty + i * 8) * C + c0 + tx];
    __syncthreads();
#pragma unroll
    for (int i = 0; i < 4; i++)
        out[(size_t)(c0 + ty + i * 8) * R + r0 + tx] = (__bf16)tile[tx][ty + i * 8];
}

// ------------------------------- MFMA GEMM ---------------------------------
// C[M][N] = A[M][K] @ Bt[N][K]^T + bias.  TM x 128 tile, 256 threads (4
// waves), wave covers (TM/2) x 64 as (TM/32)x4 frags of 16x16, BK=32.
// Double-buffered global_load_lds staging with next-tile prefetch.
// EPI 0: scatter to Q (scaled), K, Vt (bf16).  EPI 1: fp32 out + bias.

template <int EPI, int TM>
__global__ __launch_bounds__(256) void gemm_bt_kernel(
    const __bf16* __restrict__ A, const __bf16* __restrict__ Bt,
    const float* __restrict__ bias, float* __restrict__ Cout,
    __bf16* __restrict__ Q, __bf16* __restrict__ Kb, __bf16* __restrict__ Vt,
    int M, int N, int K) {
    constexpr int MI  = TM / 32;          // m-frags per wave (4 or 2)
    constexpr int WM  = MI * 16;          // rows per wave (64 or 32)
    constexpr int ACH = TM / 64;          // A-chunk rounds (2 or 1)
    __shared__ __bf16 As[2][TM * 32];     // row-major [TM][32]
    __shared__ __bf16 Bs[2][128 * 32];

    const int tid  = threadIdx.x;
    const int lane = tid & 63;
    const int wave = tid >> 6;
    const int lo   = lane & 15;
    const int qd   = lane >> 4;
    const int wm   = (wave >> 1) * WM;
    const int wn   = (wave & 1) * 64;
    const int m0   = blockIdx.y * TM;
    const int n0   = blockIdx.x * 128;

    // chunk g (16B) -> LDS byte g*16; global row g>>2, k-off (g&3)*8
    const __bf16* gA[ACH];
    const __bf16* gB[2];
#pragma unroll
    for (int c = 0; c < ACH; c++) {
        int g = tid + 256 * c;
        gA[c] = A + (size_t)(m0 + (g >> 2)) * K + (g & 3) * 8;
    }
#pragma unroll
    for (int c = 0; c < 2; c++) {
        int g = tid + 256 * c;
        gB[c] = Bt + (size_t)(n0 + (g >> 2)) * K + (g & 3) * 8;
    }

    f32x4 acc[MI][4] = {};
    const int nk = K >> 5;

    // prologue: stage tile 0 into buffer 0
#pragma unroll
    for (int c = 0; c < ACH; c++)
        GLOAD16(gA[c], (__bf16*)As[0] + (tid + 256 * c) * 8);
#pragma unroll
    for (int c = 0; c < 2; c++)
        GLOAD16(gB[c], (__bf16*)Bs[0] + (tid + 256 * c) * 8);
    DRAIN_ALL();
    __syncthreads();

    for (int kt = 0; kt < nk; kt++) {
        const int cur = kt & 1;
        if (kt + 1 < nk) {               // prefetch next tile into other buffer
            const int k0n = (kt + 1) << 5;
#pragma unroll
            for (int c = 0; c < ACH; c++)
                GLOAD16(gA[c] + k0n, (__bf16*)As[1 - cur] + (tid + 256 * c) * 8);
#pragma unroll
            for (int c = 0; c < 2; c++)
                GLOAD16(gB[c] + k0n, (__bf16*)Bs[1 - cur] + (tid + 256 * c) * 8);
        }
        bf16x8 af[MI], bfr[4];
#pragma unroll
        for (int i = 0; i < MI; i++)
            af[i] = *(const bf16x8*)(As[cur] + (wm + i * 16 + lo) * 32 + qd * 8);
#pragma unroll
        for (int j = 0; j < 4; j++)
            bfr[j] = *(const bf16x8*)(Bs[cur] + (wn + j * 16 + lo) * 32 + qd * 8);
#pragma unroll
        for (int i = 0; i < MI; i++)
#pragma unroll
            for (int j = 0; j < 4; j++)
                acc[i][j] = MFMA16(af[i], bfr[j], acc[i][j]);
        DRAIN_ALL();                     // prefetch landed + all LDS ops done
        __syncthreads();
    }

#pragma unroll
    for (int i = 0; i < MI; i++) {
#pragma unroll
        for (int j = 0; j < 4; j++) {
#pragma unroll
            for (int r = 0; r < 4; r++) {
                int gm = m0 + wm + i * 16 + qd * 4 + r;   // C/D row
                int gn = n0 + wn + j * 16 + lo;           // C/D col
                float v = acc[i][j][r] + bias[gn];
                if (EPI == 1) {
                    Cout[(size_t)gm * N + gn] = v;
                } else {
                    int which = gn >> 10;                 // 0=q 1=k 2=v
                    int bh = ((gm >> 11) << 4) + ((gn >> 6) & 15);
                    int dd = gn & 63;
                    int t  = gm & (T_ - 1);
                    if (which == 0)
                        Q[((size_t)bh * T_ + t) * DH_ + dd] = (__bf16)(v * QSCALE);
                    else if (which == 1)
                        Kb[((size_t)bh * T_ + t) * DH_ + dd] = (__bf16)v;
                    else
                        Vt[((size_t)bh * DH_ + dd) * T_ + t] = (__bf16)v;
                }
            }
        }
    }
}

// ---------------------------- flash attention ------------------------------
// Persistent snake schedule: 1024 work items = (head 0..31) x (64-row q-tile
// x 0..31), cost x+1 key-tiles.  Sorted heavy-first: item i -> x = 31-(i>>5),
// head = i&31 (head pinned to XCD i&7 under round-robin dispatch).  Block k
// takes item k; blocks >=512 also take item 1535-k (lightest).  Per-block
// cost 17..32 tiles -> balanced; grid 768 = 3 blocks/CU (LDS 41 KB).
// Softmax: shared per-wave m (exact; m arbitrary per row if consistent),
// wave-uniform skip-rescale, row sums via MFMA with ones-B (no shuffle
// cascades).  K/V 64-key LDS tiles, dbuf + prefetch, XOR-swizzled rows.

__global__ __launch_bounds__(256) void attn_kernel(
    const __bf16* __restrict__ Q,   // [BH][T][64], pre-scaled
    const __bf16* __restrict__ Kb,  // [BH][T][64]
    const __bf16* __restrict__ Vt,  // [BH][64][T]
    __bf16* __restrict__ O) {       // [B][T][H*64]
    __shared__ __bf16 Ks[2][64 * 64];     // [key][d]  2 x 8 KB, swizzled
    __shared__ __bf16 Vs[2][64 * 64];     // [d][key]  2 x 8 KB, swizzled
    __shared__ __bf16 Ps[4][16][72];      // per-wave P transpose buffer

    const int tid  = threadIdx.x;
    const int wave = tid >> 6;
    const int lane = tid & 63;
    const int lo   = lane & 15;
    const int qd   = lane >> 4;

    // staging decode: chunk g -> LDS byte g*16; row=g>>3, cc_lds=g&7,
    // global cc = cc_lds ^ (row&7)
    const int g0  = wave * 128 + lane;
    const int g1  = g0 + 64;
    const int r0s = g0 >> 3, c0s = (g0 & 7) ^ (r0s & 7);
    const int r1s = g1 >> 3, c1s = (g1 & 7) ^ (r1s & 7);
    const int so0 = wave * 1024;
    const int so1 = wave * 1024 + 512;

    bf16x8 ones;
#pragma unroll
    for (int i = 0; i < 8; i++) ones[i] = (__bf16)1.0f;

    const int kblk   = blockIdx.x;
    const int nitems = (kblk >= 512) ? 2 : 1;

    for (int it = 0; it < nitems; it++) {
        const int item = (it == 0) ? kblk : (1535 - kblk);
        const int x    = 31 - (item >> 5);
        const int bh   = item & 31;
        const int b    = bh >> 4;
        const int h    = bh & 15;
        const int q0   = x * 64 + wave * 16;

        const __bf16* Qh = Q + (size_t)bh * T_ * DH_;
        const __bf16* Kh = Kb + (size_t)bh * T_ * DH_;
        const __bf16* Vh = Vt + (size_t)bh * DH_ * T_;

        // Q A-frags: lane holds Q[q0+lo][half*32 + qd*8 + j]
        bf16x8 qa0 = *(const bf16x8*)(Qh + (size_t)(q0 + lo) * DH_ + qd * 8);
        bf16x8 qa1 = *(const bf16x8*)(Qh + (size_t)(q0 + lo) * DH_ + 32 + qd * 8);

        f32x4 oacc[4] = {};
        float m = -1e30f;
        float lrow[4] = {0.0f, 0.0f, 0.0f, 0.0f};
        const int qrow  = q0 + qd * 4;
        const int ntile = x + 1;

        // prologue: stage tile 0 into buffer 0 (prev item fully synced)
        GLOAD16(Kh + (size_t)r0s * DH_ + c0s * 8, Ks[0] + so0);
        GLOAD16(Kh + (size_t)r1s * DH_ + c1s * 8, Ks[0] + so1);
        GLOAD16(Vh + (size_t)r0s * T_ + c0s * 8, Vs[0] + so0);
        GLOAD16(Vh + (size_t)r1s * T_ + c1s * 8, Vs[0] + so1);
        DRAIN_ALL();
        __syncthreads();

        for (int t = 0; t < ntile; t++) {
            const int j0  = t << 6;
            const int cur = t & 1;
            if (t + 1 < ntile) {         // prefetch next K/V tile
                const int j0n = j0 + 64;
                GLOAD16(Kh + (size_t)(j0n + r0s) * DH_ + c0s * 8, Ks[1 - cur] + so0);
                GLOAD16(Kh + (size_t)(j0n + r1s) * DH_ + c1s * 8, Ks[1 - cur] + so1);
                GLOAD16(Vh + (size_t)r0s * T_ + j0n + c0s * 8, Vs[1 - cur] + so0);
                GLOAD16(Vh + (size_t)r1s * T_ + j0n + c1s * 8, Vs[1 - cur] + so1);
            }

            // ---- S = Q @ K^T, 64 keys as 4 col-groups of 16 ----
            f32x4 s[4] = {};
#pragma unroll
            for (int g = 0; g < 4; g++) {
                const int row = g * 16 + lo;
                const __bf16* kr = Ks[cur] + row * 64;
                bf16x8 kb0 = *(const bf16x8*)(kr + ((qd ^ (row & 7)) << 3));
                bf16x8 kb1 = *(const bf16x8*)(kr + (((4 + qd) ^ (row & 7)) << 3));
                s[g] = MFMA16(qa0, kb0, s[g]);
                s[g] = MFMA16(qa1, kb1, s[g]);
            }

            // ---- causal mask (diagonal tile only; wave-uniform gate) ----
            if (j0 + 63 > q0) {
#pragma unroll
                for (int g = 0; g < 4; g++) {
                    const int col = j0 + g * 16 + lo;
#pragma unroll
                    for (int r = 0; r < 4; r++)
                        s[g][r] = (col <= qrow + r) ? s[g][r] : -1e30f;
                }
            }

            // ---- shared per-wave max (exact: m arbitrary if consistent) ----
            float lm = s[0][0];
#pragma unroll
            for (int g = 0; g < 4; g++)
#pragma unroll
                for (int r = 0; r < 4; r++) lm = fmaxf(lm, s[g][r]);
#pragma unroll
            for (int off = 1; off < 64; off <<= 1)
                lm = fmaxf(lm, __shfl_xor(lm, off));
            const float mnew = fmaxf(m, lm);
            if (mnew > m) {              // wave-uniform; skipped once m settles
                const float alpha = __builtin_amdgcn_exp2f(m - mnew);
#pragma unroll
                for (int r = 0; r < 4; r++) lrow[r] *= alpha;
#pragma unroll
                for (int c = 0; c < 4; c++)
#pragma unroll
                    for (int r = 0; r < 4; r++) oacc[c][r] *= alpha;
                m = mnew;
            }

            // ---- P = exp2(S - m): C-layout -> per-wave LDS -> A-layout ----
#pragma unroll
            for (int g = 0; g < 4; g++)
#pragma unroll
                for (int r = 0; r < 4; r++)
                    Ps[wave][qd * 4 + r][g * 16 + lo] =
                        (__bf16)__builtin_amdgcn_exp2f(s[g][r] - m);
            __asm__ volatile("s_waitcnt lgkmcnt(0)" ::: "memory");
            bf16x8 pa0 = *(const bf16x8*)(&Ps[wave][lo][qd * 8]);
            bf16x8 pa1 = *(const bf16x8*)(&Ps[wave][lo][32 + qd * 8]);

            // ---- row sums via MFMA ones-trick + O += P @ V ----
            f32x4 ps = {};
            ps = MFMA16(pa0, ones, ps);
            ps = MFMA16(pa1, ones, ps);
#pragma unroll
            for (int c = 0; c < 4; c++) {
                const int row = c * 16 + lo;
                const __bf16* vr = Vs[cur] + row * 64;
                bf16x8 vb0 = *(const bf16x8*)(vr + ((qd ^ (row & 7)) << 3));
                bf16x8 vb1 = *(const bf16x8*)(vr + (((4 + qd) ^ (row & 7)) << 3));
                oacc[c] = MFMA16(pa0, vb0, oacc[c]);
                oacc[c] = MFMA16(pa1, vb1, oacc[c]);
            }
#pragma unroll
            for (int r = 0; r < 4; r++) lrow[r] += ps[r];

            DRAIN_ALL();                 // prefetch landed + all LDS ops done
            __syncthreads();
        }

        // ---- normalize + store O as [B][T][H*64] bf16 ----
        float inv[4];
#pragma unroll
        for (int r = 0; r < 4; r++) inv[r] = 1.0f / lrow[r];
#pragma unroll
        for (int c = 0; c < 4; c++) {
#pragma unroll
            for (int r = 0; r < 4; r++) {
                float val = oacc[c][r] * inv[r];
                size_t idx = ((size_t)b * T_ + (qrow + r)) * D_ + h * DH_ + c * 16 + lo;
                O[idx] = (__bf16)val;
            }
        }
    }
}

// -------------------------------- launcher ---------------------------------

extern "C" void kernel_launch(void* const* d_in, const int* in_sizes, int n_in,
                              void* d_out, int out_size, void* d_ws, size_t ws_size,
                              hipStream_t stream) {
    const float* x      = (const float*)d_in[0];
    const float* w_attn = (const float*)d_in[1];
    const float* b_attn = (const float*)d_in[2];
    const float* w_proj = (const float*)d_in[3];
    const float* b_proj = (const float*)d_in[4];
    float* out = (float*)d_out;

    const size_t MB = (size_t)1 << 20;
    if (ws_size < 48 * MB) return;   // need 48 MB scratch

    char* ws = (char*)d_ws;
    __bf16* xb     = (__bf16*)(ws);              //  8 MB  [M][D]
    __bf16* wattnT = (__bf16*)(ws + 8 * MB);     //  6 MB  [3D][D]
    __bf16* wprojT = (__bf16*)(ws + 14 * MB);    //  2 MB  [D][D]
    __bf16* Qb     = (__bf16*)(ws + 16 * MB);    //  8 MB  [BH][T][64]
    __bf16* Kb     = (__bf16*)(ws + 24 * MB);    //  8 MB  [BH][T][64]
    __bf16* Vt     = (__bf16*)(ws + 32 * MB);    //  8 MB  [BH][64][T]
    __bf16* Ob     = (__bf16*)(ws + 40 * MB);    //  8 MB  [M][D]

    // 1. converts
    f32_to_bf16_kernel<<<(M_ * D_) / 1024, 256, 0, stream>>>(x, xb, M_ * D_);
    transpose_bf16_kernel<<<dim3(N1_ / 32, D_ / 32), dim3(32, 8), 0, stream>>>(
        w_attn, wattnT, D_, N1_);
    transpose_bf16_kernel<<<dim3(D_ / 32, D_ / 32), dim3(32, 8), 0, stream>>>(
        w_proj, wprojT, D_, D_);
    // 2. QKV GEMM -> Q(scaled)/K/Vt
    gemm_bt_kernel<0, 128><<<dim3(N1_ / 128, M_ / 128), 256, 0, stream>>>(
        xb, wattnT, b_attn, nullptr, Qb, Kb, Vt, M_, N1_, D_);
    // 3. causal flash attention (persistent snake schedule, 3 blocks/CU)
    attn_kernel<<<dim3(768), 256, 0, stream>>>(Qb, Kb, Vt, Ob);
    // 4. output projection (fp32 + bias), 64-row tiles for 2 blocks/CU
    gemm_bt_kernel<1, 64><<<dim3(D_ / 128, M_ / 64), 256, 0, stream>>>(
        Ob, wprojT, b_proj, out, nullptr, nullptr, nullptr, M_, D_, D_);
}